// Round 7
// baseline (271.807 us; speedup 1.0000x reference)
//
#include <hip/hip_runtime.h>
#include <hip/hip_fp16.h>

#define D 128
#define SCAN_B 256

typedef __attribute__((ext_vector_type(8))) _Float16 f16x8;
typedef __attribute__((ext_vector_type(4))) float f32x4;

typedef __attribute__((address_space(1))) const void gas_t;
typedef __attribute__((address_space(3))) void las_t;

// ---- hierarchical exclusive scan ----
__global__ void scan_pass1(const int* __restrict__ cnt, int* __restrict__ rs,
                           int* __restrict__ bsum, int N) {
    __shared__ int lds[SCAN_B];
    int tid = threadIdx.x;
    int i = blockIdx.x * SCAN_B + tid;
    int v = (i < N) ? cnt[i] : 0;
    lds[tid] = v;
    __syncthreads();
    for (int o = 1; o < SCAN_B; o <<= 1) {
        int t = (tid >= o) ? lds[tid - o] : 0;
        __syncthreads();
        lds[tid] += t;
        __syncthreads();
    }
    if (i < N) rs[i] = lds[tid] - v;
    if (tid == SCAN_B - 1) bsum[blockIdx.x] = lds[tid];
}

__global__ void scan_pass2(int* __restrict__ bsum, int nb) {
    __shared__ int lds[SCAN_B];
    int tid = threadIdx.x;
    int v = (tid < nb) ? bsum[tid] : 0;
    lds[tid] = v;
    __syncthreads();
    for (int o = 1; o < SCAN_B; o <<= 1) {
        int t = (tid >= o) ? lds[tid - o] : 0;
        __syncthreads();
        lds[tid] += t;
        __syncthreads();
    }
    if (tid < nb) bsum[tid] = lds[tid] - v;
}

__global__ void scan_pass3(int* __restrict__ rs, int* __restrict__ cursor,
                           const int* __restrict__ bsum, const int* __restrict__ cnt,
                           float* __restrict__ inv, int N) {
    int i = blockIdx.x * SCAN_B + threadIdx.x;
    if (i < N) {
        int v = rs[i] + bsum[blockIdx.x];
        rs[i] = v;
        cursor[i] = v;
        inv[i] = 1.0f / (float)max(cnt[i], 1);
    }
}

__global__ void fill_kernel(const int* __restrict__ ei, int E,
                            int* __restrict__ cursor, int* __restrict__ csr) {
    int e = blockIdx.x * blockDim.x + threadIdx.x;
    if (e < E) {
        int src = ei[e], dst = ei[E + e];
        int pos = atomicAdd(&cursor[dst], 1);
        csr[pos] = src;
    }
}

// ---- fused prologue: weight pack | fp32->f16 hi/lo cvt | degree count ----
__global__ void prologue_kernel(const float* __restrict__ W1l, const float* __restrict__ W1r,
                                const float* __restrict__ W2l, const float* __restrict__ W2r,
                                const float* __restrict__ Wf, unsigned short* __restrict__ pw,
                                const float* __restrict__ x, __half* __restrict__ xh,
                                __half* __restrict__ xl, int n8,
                                const int* __restrict__ ei, int E, int* __restrict__ cnt) {
    int t = blockIdx.x * blockDim.x + threadIdx.x;
    if (t < 10240) {
        int idx = t;
        int w = idx >> 11;
        int r = idx & 2047;
        int ks = r >> 9;
        int tt = (r >> 6) & 7;
        int lane = r & 63;
        int q = lane >> 4, n = lane & 15;
        const float* W = (w == 0) ? W1l : (w == 1) ? W1r : (w == 2) ? W2l : (w == 3) ? W2r : Wf;
        unsigned short* dh = pw + (size_t)w * 32768;
        unsigned short* dl = dh + 16384;
        int off = ((ks * 8 + tt) * 64 + lane) * 8;
#pragma unroll
        for (int j = 0; j < 8; j++) {
            float v = W[(size_t)(ks * 32 + q * 8 + j) * D + tt * 16 + n];
            __half hb = __float2half_rn(v);
            dh[off + j] = __half_as_ushort(hb);
            dl[off + j] = __half_as_ushort(__float2half_rn(v - __half2float(hb)));
        }
    } else if (t < 10240 + n8) {
        int i = t - 10240;
        const float4* x4 = (const float4*)x;
        float4 a = x4[2 * i], b = x4[2 * i + 1];
        float v[8] = {a.x, a.y, a.z, a.w, b.x, b.y, b.z, b.w};
        uint4 oh, ol;
        __half2* ph = (__half2*)&oh;
        __half2* pl = (__half2*)&ol;
#pragma unroll
        for (int jj = 0; jj < 4; jj++) {
            __half h0 = __float2half_rn(v[2 * jj]);
            __half h1 = __float2half_rn(v[2 * jj + 1]);
            ph[jj] = __halves2half2(h0, h1);
            pl[jj] = __halves2half2(__float2half_rn(v[2 * jj] - __half2float(h0)),
                                    __float2half_rn(v[2 * jj + 1] - __half2float(h1)));
        }
        ((uint4*)xh)[i] = oh;
        ((uint4*)xl)[i] = ol;
    } else {
        int e = t - 10240 - n8;
        if (e < E) atomicAdd(&cnt[ei[E + e]], 1);
    }
}

__device__ __forceinline__ void acc8(uint4 v, float* s) {
    const __half2* h = reinterpret_cast<const __half2*>(&v);
    float2 f0 = __half22float2(h[0]);
    float2 f1 = __half22float2(h[1]);
    float2 f2 = __half22float2(h[2]);
    float2 f3 = __half22float2(h[3]);
    s[0] += f0.x; s[1] += f0.y; s[2] += f1.x; s[3] += f1.y;
    s[4] += f2.x; s[5] += f2.y; s[6] += f3.x; s[7] += f3.y;
}

__device__ __forceinline__ void split_f16(const float* v, uint4& hi, uint4& lo) {
    __half2* ph = (__half2*)&hi;
    __half2* pl = (__half2*)&lo;
#pragma unroll
    for (int jj = 0; jj < 4; jj++) {
        __half h0 = __float2half_rn(v[2 * jj]);
        __half h1 = __float2half_rn(v[2 * jj + 1]);
        ph[jj] = __halves2half2(h0, h1);
        pl[jj] = __halves2half2(__float2half_rn(v[2 * jj] - __half2float(h0)),
                                __float2half_rn(v[2 * jj + 1] - __half2float(h1)));
    }
}

// ---- fused gather-aggregate + full-row-wave MFMA GEMM ----
// block = 4 waves x 16 rows = 64 rows. grid = ceil(N/64). K=256 (agg | x-or-h).
// Lane (c,q) gathers exactly its A-fragment slice (cols q*8+j of each 32-wide k-subtile)
// from neighbor rows, accumulates in f32 regs, splits to f16 hi/lo in-register.
// Weights staged via global_load_lds double-buffer (round-6 proven structure).
template <int LAYER>
__global__ __launch_bounds__(256) void fused_gemm(
        const int* __restrict__ csr, const int* __restrict__ rs,
        const int* __restrict__ cnt, const float* __restrict__ inv,
        const uint4* __restrict__ Gsrc,                                // gather rows (hi)
        const uint4* __restrict__ Ah1, const uint4* __restrict__ Al1,  // x or h1 (root side)
        const uint4* __restrict__ W0h, const uint4* __restrict__ W0l,
        const uint4* __restrict__ W1h, const uint4* __restrict__ W1l,
        const float* __restrict__ bias,
        const uint4* __restrict__ W2h, const uint4* __restrict__ W2l,
        const float* __restrict__ bias2,
        float* out, __half* Hout, int N) {
    __shared__ uint4 smem4[2048];   // 32 KB: W double-buffer; LAYER2 reuses for H staging
    const int GS = (LAYER == 1) ? 16 : 32;   // gather row stride in uint4

    const int tid = threadIdx.x;
    const int lane = tid & 63;
    const int wave = tid >> 6;
    const int c = lane & 15;
    const int q = lane >> 4;
    const int R = blockIdx.x * 64 + wave * 16;
    const int row0 = min(R + c, N - 1);
    const size_t rbA1 = (size_t)row0 * GS + q;

#define STAGE_W(ks_, b_)                                                                   \
    do {                                                                                   \
        const uint4* sh_ = (((ks_) < 4) ? W0h : W1h) + (size_t)((ks_) & 3) * 512;          \
        const uint4* sl_ = (((ks_) < 4) ? W0l : W1l) + (size_t)((ks_) & 3) * 512;          \
        const uint4* s_ = ((wave < 2) ? sh_ : sl_) + ((wave & 1) * 256 + lane);            \
        uint4* d_ = smem4 + (b_) * 1024 + (wave >> 1) * 512 + (wave & 1) * 256;            \
        __builtin_amdgcn_global_load_lds((gas_t*)(s_), (las_t*)(d_), 16, 0, 0);            \
        __builtin_amdgcn_global_load_lds((gas_t*)(s_ + 64), (las_t*)(d_ + 64), 16, 0, 0);  \
        __builtin_amdgcn_global_load_lds((gas_t*)(s_ + 128), (las_t*)(d_ + 128), 16, 0, 0);\
        __builtin_amdgcn_global_load_lds((gas_t*)(s_ + 192), (las_t*)(d_ + 192), 16, 0, 0);\
    } while (0)

    // stage first two weight buffers (async, zero VGPR) + root-side A frags upfront
    STAGE_W(0, 0);
    STAGE_W(1, 1);
    uint4 Xs_h[4], Xs_l[4];
#pragma unroll
    for (int kl = 0; kl < 4; kl++) {
        Xs_h[kl] = Ah1[rbA1 + kl * 4];
        Xs_l[kl] = Al1[rbA1 + kl * 4];
    }

    // ---- gather-aggregate this lane's fragment slice ----
    int deg = cnt[row0];
    int st = rs[row0];
    float iv = inv[row0];
    float s[4][8];
#pragma unroll
    for (int ks = 0; ks < 4; ks++)
#pragma unroll
        for (int j = 0; j < 8; j++) s[ks][j] = 0.0f;

    int i = 0;
    for (; i + 2 <= deg; i += 2) {
        int n0 = csr[st + i], n1 = csr[st + i + 1];
        const uint4* g0 = Gsrc + (size_t)n0 * GS + q;
        const uint4* g1 = Gsrc + (size_t)n1 * GS + q;
        uint4 a0 = g0[0], a1 = g0[4], a2 = g0[8], a3 = g0[12];
        uint4 b0 = g1[0], b1 = g1[4], b2 = g1[8], b3 = g1[12];
        acc8(a0, s[0]); acc8(a1, s[1]); acc8(a2, s[2]); acc8(a3, s[3]);
        acc8(b0, s[0]); acc8(b1, s[1]); acc8(b2, s[2]); acc8(b3, s[3]);
    }
    if (i < deg) {
        int n0 = csr[st + i];
        const uint4* g0 = Gsrc + (size_t)n0 * GS + q;
        uint4 a0 = g0[0], a1 = g0[4], a2 = g0[8], a3 = g0[12];
        acc8(a0, s[0]); acc8(a1, s[1]); acc8(a2, s[2]); acc8(a3, s[3]);
    }

    uint4 Agg_h[4], Agg_l[4];
#pragma unroll
    for (int ks = 0; ks < 4; ks++) {
        float v[8];
#pragma unroll
        for (int j = 0; j < 8; j++) v[j] = s[ks][j] * iv;
        split_f16(v, Agg_h[ks], Agg_l[ks]);
    }

    asm volatile("s_waitcnt vmcnt(0)" ::: "memory");
    __syncthreads();

    f32x4 acc[8];
#pragma unroll
    for (int t = 0; t < 8; t++)
#pragma unroll
        for (int r = 0; r < 4; r++) acc[t][r] = 0.0f;

#pragma unroll
    for (int ks = 0; ks < 8; ks++) {
        const int b = ks & 1;
        const uint4* wb = smem4 + b * 1024;
        f16x8 ah = __builtin_bit_cast(f16x8, (ks < 4) ? Agg_h[ks & 3] : Xs_h[ks & 3]);
        f16x8 al = __builtin_bit_cast(f16x8, (ks < 4) ? Agg_l[ks & 3] : Xs_l[ks & 3]);
#pragma unroll
        for (int t = 0; t < 8; t++) {
            f16x8 bh = __builtin_bit_cast(f16x8, wb[t * 64 + lane]);
            f16x8 bl = __builtin_bit_cast(f16x8, wb[512 + t * 64 + lane]);
            acc[t] = __builtin_amdgcn_mfma_f32_16x16x32_f16(ah, bh, acc[t], 0, 0, 0);
            acc[t] = __builtin_amdgcn_mfma_f32_16x16x32_f16(al, bh, acc[t], 0, 0, 0);
            acc[t] = __builtin_amdgcn_mfma_f32_16x16x32_f16(ah, bl, acc[t], 0, 0, 0);
        }
        if (ks < 7) {
            asm volatile("s_waitcnt vmcnt(0)" ::: "memory");
            __syncthreads();
            if (ks < 6) STAGE_W(ks + 2, b);   // overwrite just-consumed buffer
        }
    }

    // bias + row L2-norm (whole row in this wave: 16-lane shfl reduce) + relu
#pragma unroll
    for (int t = 0; t < 8; t++) {
        float bv = bias[t * 16 + c];
#pragma unroll
        for (int r = 0; r < 4; r++) acc[t][r] += bv;
    }
#pragma unroll
    for (int r = 0; r < 4; r++) {
        float v = 0.0f;
#pragma unroll
        for (int t = 0; t < 8; t++) v += acc[t][r] * acc[t][r];
        v += __shfl_xor(v, 1, 16);
        v += __shfl_xor(v, 2, 16);
        v += __shfl_xor(v, 4, 16);
        v += __shfl_xor(v, 8, 16);
        float rn = 1.0f / fmaxf(sqrtf(v), 1e-12f);
#pragma unroll
        for (int t = 0; t < 8; t++) acc[t][r] = fmaxf(acc[t][r] * rn, 0.0f);
    }

    if (LAYER == 1) {
        // write h1 row-interleaved (hi 128 | lo 128 halfs per row) to workspace
#pragma unroll
        for (int t = 0; t < 8; t++)
#pragma unroll
            for (int r = 0; r < 4; r++) {
                int row = R + q * 4 + r;
                if (row < N) {
                    float v = acc[t][r];
                    __half h = __float2half_rn(v);
                    size_t base = (size_t)row * 256;
                    Hout[base + t * 16 + c] = h;
                    Hout[base + 128 + t * 16 + c] = __float2half_rn(v - __half2float(h));
                }
            }
        return;
    }

    // ---- fused FC ----
    __syncthreads();  // all waves done reading the weight double-buffer
    // H staging (wave-private 8 KB: hi 4 KB | lo 4 KB), XOR-swizzled uint4 index
    unsigned short* hw = (unsigned short*)(smem4 + wave * 512);
#pragma unroll
    for (int t = 0; t < 8; t++)
#pragma unroll
        for (int r = 0; r < 4; r++) {
            int m = q * 4 + r;
            float v = acc[t][r];
            __half h = __float2half_rn(v);
            int j4 = (t * 2 + (c >> 3)) ^ (m & 7);
            int off = m * 128 + j4 * 8 + (c & 7);
            hw[off] = __half_as_ushort(h);
            hw[2048 + off] = __half_as_ushort(__float2half_rn(v - __half2float(h)));
        }
    uint4 a2h_[4], a2l_[4];
#pragma unroll
    for (int k2 = 0; k2 < 4; k2++) {
        int r4 = (k2 * 4 + q) ^ (c & 7);
        a2h_[k2] = *(const uint4*)(hw + c * 128 + r4 * 8);
        a2l_[k2] = *(const uint4*)(hw + 2048 + c * 128 + r4 * 8);
    }

    f32x4 acc2[8];
#pragma unroll
    for (int t = 0; t < 8; t++) {
        float bv = bias2[t * 16 + c];
#pragma unroll
        for (int r = 0; r < 4; r++) acc2[t][r] = bv;
    }
#pragma unroll
    for (int k2 = 0; k2 < 4; k2++) {
        const uint4* Wh = W2h + (size_t)k2 * 512 + lane;
        const uint4* Wl = W2l + (size_t)k2 * 512 + lane;
        f16x8 ah = __builtin_bit_cast(f16x8, a2h_[k2]);
        f16x8 al = __builtin_bit_cast(f16x8, a2l_[k2]);
#pragma unroll
        for (int t = 0; t < 8; t++) {
            f16x8 bh = __builtin_bit_cast(f16x8, Wh[t * 64]);
            f16x8 bl = __builtin_bit_cast(f16x8, Wl[t * 64]);
            acc2[t] = __builtin_amdgcn_mfma_f32_16x16x32_f16(ah, bh, acc2[t], 0, 0, 0);
            acc2[t] = __builtin_amdgcn_mfma_f32_16x16x32_f16(al, bh, acc2[t], 0, 0, 0);
            acc2[t] = __builtin_amdgcn_mfma_f32_16x16x32_f16(ah, bl, acc2[t], 0, 0, 0);
        }
    }

#pragma unroll
    for (int t = 0; t < 8; t++)
#pragma unroll
        for (int r = 0; r < 4; r++) {
            int row = R + q * 4 + r;
            if (row < N) out[(size_t)row * D + t * 16 + c] = acc2[t][r];
        }
#undef STAGE_W
}

extern "C" void kernel_launch(void* const* d_in, const int* in_sizes, int n_in,
                              void* d_out, int out_size, void* d_ws, size_t ws_size,
                              hipStream_t stream) {
    const float* x   = (const float*)d_in[0];
    const int*   ei  = (const int*)d_in[1];
    const float* W1l = (const float*)d_in[2];
    const float* b1  = (const float*)d_in[3];
    const float* W1r = (const float*)d_in[4];
    const float* W2l = (const float*)d_in[5];
    const float* b2  = (const float*)d_in[6];
    const float* W2r = (const float*)d_in[7];
    const float* Wf  = (const float*)d_in[8];
    const float* bf  = (const float*)d_in[9];
    float* out = (float*)d_out;

    int N = in_sizes[0] / D;
    int E = in_sizes[1] / 2;

    // ws: Xh | Xl (N*D halfs) | H1 (N*256 halfs, interleaved hi|lo) | inv f | rs i | cnt i |
    //     cursor i | bsum[256] i | csr[E] i | pw[5*32768] ush   (~56 MB)
    __half* Xh  = (__half*)d_ws;
    __half* Xl  = Xh + (size_t)N * D;
    __half* H1  = Xl + (size_t)N * D;
    float* inv  = (float*)(H1 + (size_t)N * 256);
    int*   rs     = (int*)(inv + N);
    int*   cnt    = rs + N;
    int*   cursor = cnt + N;
    int*   bsum   = cursor + N;
    int*   csr    = bsum + 256;
    unsigned short* pw = (unsigned short*)(csr + E);
    unsigned short* p1lh = pw + 0 * 32768, *p1ll = p1lh + 16384;
    unsigned short* p1rh = pw + 1 * 32768, *p1rl = p1rh + 16384;
    unsigned short* p2lh = pw + 2 * 32768, *p2ll = p2lh + 16384;
    unsigned short* p2rh = pw + 3 * 32768, *p2rl = p2rh + 16384;
    unsigned short* pfh  = pw + 4 * 32768, *pfl  = pfh + 16384;

    int nb = (N + SCAN_B - 1) / SCAN_B;
    int n8 = N * 16;

    hipMemsetAsync(cnt, 0, (size_t)N * sizeof(int), stream);
    int pro_threads = 10240 + n8 + E;
    prologue_kernel<<<(pro_threads + 255) / 256, 256, 0, stream>>>(
        W1l, W1r, W2l, W2r, Wf, pw, x, Xh, Xl, n8, ei, E, cnt);
    scan_pass1<<<nb, SCAN_B, 0, stream>>>(cnt, rs, bsum, N);
    scan_pass2<<<1, SCAN_B, 0, stream>>>(bsum, nb);
    scan_pass3<<<nb, SCAN_B, 0, stream>>>(rs, cursor, bsum, cnt, inv, N);
    fill_kernel<<<(E + 255) / 256, 256, 0, stream>>>(ei, E, cursor, csr);

    int gemm_blocks = (N + 63) / 64;

    // layer 1: fused gather(Xh) + GEMM(agg | Xh/Xl) -> h1 interleaved in ws
    fused_gemm<1><<<gemm_blocks, 256, 0, stream>>>(
        csr, rs, cnt, inv,
        (const uint4*)Xh, (const uint4*)Xh, (const uint4*)Xl,
        (const uint4*)p1lh, (const uint4*)p1ll, (const uint4*)p1rh, (const uint4*)p1rl, b1,
        nullptr, nullptr, nullptr, nullptr, H1, N);

    // layer 2: fused gather(H1-hi) + GEMM(agg | H1 hi/lo) + fused FC -> fp32 out
    fused_gemm<2><<<gemm_blocks, 256, 0, stream>>>(
        csr, rs, cnt, inv,
        (const uint4*)H1, (const uint4*)H1, (const uint4*)H1 + 16,
        (const uint4*)p2lh, (const uint4*)p2ll, (const uint4*)p2rh, (const uint4*)p2rl, b2,
        (const uint4*)pfh, (const uint4*)pfl, bf, out, nullptr, N);
}